// Round 9
// baseline (784.364 us; speedup 1.0000x reference)
//
#include <hip/hip_runtime.h>

// ---------------- problem constants ----------------
#define N_NODES 32768
#define E_EDGES 524288
#define F_IN    215
#define H_DIM   256
#define T_TYPES 8
#define L_LAYERS 3
#define B_GRAPHS 32
#define MAXN_   1024
#define NT_BINS (N_NODES * T_TYPES)   // 262144

typedef float  f32x4  __attribute__((ext_vector_type(4)));
typedef __bf16 bf16x8 __attribute__((ext_vector_type(8)));

__device__ __forceinline__ unsigned short f2bf(float f) {
  union { float f; unsigned u; } v; v.f = f;
  unsigned r = v.u + 0x7fffu + ((v.u >> 16) & 1u);
  return (unsigned short)(r >> 16);
}
__device__ __forceinline__ float bf2f(unsigned short h) {
  union { unsigned u; float f; } v; v.u = ((unsigned)h) << 16;
  return v.f;
}
__device__ __forceinline__ float bflo(unsigned u) { union { unsigned x; float f; } v; v.x = u << 16; return v.f; }
__device__ __forceinline__ float bfhi(unsigned u) { union { unsigned x; float f; } v; v.x = u & 0xffff0000u; return v.f; }

typedef const __attribute__((address_space(1))) unsigned int* gas_ptr;
typedef __attribute__((address_space(3))) unsigned int* las_ptr;
__device__ __forceinline__ void gload_lds16(const unsigned short* g, unsigned short* l) {
  __builtin_amdgcn_global_load_lds((gas_ptr)g, (las_ptr)l, 16, 0, 0);
}

__device__ __forceinline__ void acc16(float* a, const uint4 v, const uint4 w) {
  a[0]  += bflo(v.x); a[1]  += bfhi(v.x);
  a[2]  += bflo(v.y); a[3]  += bfhi(v.y);
  a[4]  += bflo(v.z); a[5]  += bfhi(v.z);
  a[6]  += bflo(v.w); a[7]  += bfhi(v.w);
  a[8]  += bflo(w.x); a[9]  += bfhi(w.x);
  a[10] += bflo(w.y); a[11] += bfhi(w.y);
  a[12] += bflo(w.z); a[13] += bfhi(w.z);
  a[14] += bflo(w.w); a[15] += bfhi(w.w);
}

// ---------------- ws layout (bytes) ----------------
static constexpr size_t OFF_BIG     = 0;            // 134217728
static constexpr size_t REL_CURSOR  = 1048576;
static constexpr size_t REL_BSUM    = 2097152;
static constexpr size_t REL_WPPAD   = 33554432;
static constexpr size_t REL_HALT    = 50331648;
static constexpr size_t REL_OFFS    = 100663296;
static constexpr size_t REL_SORTED  = 104857600;
static constexpr size_t OFF_H_B     = 134217728;    // 16777216   h bf16 (N,H)
static constexpr size_t OFF_M_B     = 150994944;    // 16777216   m bf16 (N,H)
static constexpr size_t OFF_WMB     = 167772160;    // 3145728    Wm bf16 (L,T,H,H) natural
static constexpr size_t OFF_WIH     = 170917888;    // 1179648    Wih bf16
static constexpr size_t OFF_WHH     = 172097536;    // 1179648    Whh bf16
static constexpr size_t WS_REQUIRED = 173277184;    // < 175.9 MB proven safe

// ---------------- edge preprocessing: counting sort by key=(dst*8+type) ----------------
__global__ void hist_kernel(const int* __restrict__ dst, const int* __restrict__ et,
                            int* __restrict__ cnt) {
  int e = blockIdx.x * 256 + threadIdx.x;
  atomicAdd(&cnt[dst[e] * T_TYPES + et[e]], 1);
}

__global__ __launch_bounds__(1024) void scan1(const int* __restrict__ cnt,
                                              int* __restrict__ offs,
                                              int* __restrict__ bsum) {
  __shared__ int wsum[16];
  const int t = threadIdx.x, lane = t & 63, wid = t >> 6;
  const int idx = blockIdx.x * 1024 + t;
  const int v = cnt[idx];
  int x = v;
  #pragma unroll
  for (int off = 1; off < 64; off <<= 1) {
    int u = __shfl_up(x, off, 64);
    if (lane >= off) x += u;
  }
  if (lane == 63) wsum[wid] = x;
  __syncthreads();
  int wbase = 0;
  for (int i = 0; i < wid; ++i) wbase += wsum[i];
  offs[idx] = wbase + x - v;
  if (t == 1023) bsum[blockIdx.x] = wbase + x;
}

__global__ __launch_bounds__(256) void scan2(int* __restrict__ bsum) {
  __shared__ int wsum[4];
  const int t = threadIdx.x, lane = t & 63, wid = t >> 6;
  const int v = bsum[t];
  int x = v;
  #pragma unroll
  for (int off = 1; off < 64; off <<= 1) {
    int u = __shfl_up(x, off, 64);
    if (lane >= off) x += u;
  }
  if (lane == 63) wsum[wid] = x;
  __syncthreads();
  int wbase = 0;
  for (int i = 0; i < wid; ++i) wbase += wsum[i];
  __syncthreads();
  bsum[t] = wbase + x - v;
}

__global__ __launch_bounds__(1024) void scan3(int* __restrict__ offs,
                                              const int* __restrict__ bsum,
                                              int* __restrict__ cursor) {
  const int idx = blockIdx.x * 1024 + threadIdx.x;
  const int o = offs[idx] + bsum[blockIdx.x];
  offs[idx] = o;
  cursor[idx] = o;
  if (idx == 0) offs[NT_BINS] = E_EDGES;
}

__global__ void reorder_kernel(const int* __restrict__ src, const int* __restrict__ dst,
                               const int* __restrict__ et, int* __restrict__ cursor,
                               unsigned short* __restrict__ sorted) {
  int e = blockIdx.x * 256 + threadIdx.x;
  int key = dst[e] * T_TYPES + et[e];
  int p = atomicAdd(&cursor[key], 1);
  sorted[p] = (unsigned short)src[e];
}

// ---------------- conversions ----------------
// single launch for Wm + Wih + Whh
__global__ void cvt_weights(const float* __restrict__ a, const float* __restrict__ b,
                            const float* __restrict__ c,
                            unsigned short* __restrict__ oa, unsigned short* __restrict__ ob,
                            unsigned short* __restrict__ oc,
                            int na, int nb, int nc) {
  int i = blockIdx.x * 256 + threadIdx.x;
  if (i < na) { oa[i] = f2bf(a[i]); return; }
  int j = i - na;
  if (j < nb) { ob[j] = f2bf(b[j]); return; }
  int k = j - nb;
  if (k < nc) oc[k] = f2bf(c[k]);
}

__global__ void pad_cvt(const float* __restrict__ in, unsigned short* __restrict__ out,
                        int rows, int cin) {
  int i = blockIdx.x * 256 + threadIdx.x;
  if (i >= rows * 256) return;
  int r = i >> 8, c = i & 255;
  out[i] = (c < cin) ? f2bf(in[(size_t)r * cin + c]) : (unsigned short)0;
}

// ---------------- GEMM: C(N x M) = A(N x K) @ W(M x K)^T + bias (input proj) ------
__global__ __launch_bounds__(256, 2) void gemm_bt(
    const unsigned short* __restrict__ A,
    const unsigned short* __restrict__ W,
    const float* __restrict__ bias,
    unsigned short* __restrict__ C,
    int M, int K) {
  __shared__ unsigned short As[128 * 32];
  __shared__ unsigned short Bs[128 * 32];
  const int tid = threadIdx.x;
  const int lane = tid & 63;
  const int wv = tid >> 6;
  const int lrow = lane & 15;
  const int lquad = lane >> 4;
  const int bm0 = blockIdx.x * 128;
  const int bn0 = blockIdx.y * 128;
  const int srow = wv * 16 + (lane >> 2);
  const int scol = (lane & 3) * 8;

  f32x4 acc[2][8] = {};

  for (int kt = 0; kt < K; kt += 32) {
    #pragma unroll
    for (int i = 0; i < 2; ++i) {
      const int row = srow + i * 64;
      gload_lds16(A + (size_t)(bm0 + row) * K + kt + scol, &As[row * 32 + scol]);
      gload_lds16(W + (size_t)(bn0 + row) * K + kt + scol, &Bs[row * 32 + scol]);
    }
    __syncthreads();
    bf16x8 af[2], bfr[8];
    #pragma unroll
    for (int mt = 0; mt < 2; ++mt)
      af[mt] = *(const bf16x8*)(&As[(wv * 32 + mt * 16 + lrow) * 32 + lquad * 8]);
    #pragma unroll
    for (int nt = 0; nt < 8; ++nt)
      bfr[nt] = *(const bf16x8*)(&Bs[(nt * 16 + lrow) * 32 + lquad * 8]);
    #pragma unroll
    for (int mt = 0; mt < 2; ++mt)
      #pragma unroll
      for (int nt = 0; nt < 8; ++nt)
        acc[mt][nt] = __builtin_amdgcn_mfma_f32_16x16x32_bf16(af[mt], bfr[nt], acc[mt][nt], 0, 0, 0);
    __syncthreads();
  }

  #pragma unroll
  for (int mt = 0; mt < 2; ++mt) {
    #pragma unroll
    for (int r = 0; r < 4; ++r) {
      const int grow = bm0 + wv * 32 + mt * 16 + lquad * 4 + r;
      #pragma unroll
      for (int nt = 0; nt < 8; ++nt) {
        const int gcol = bn0 + nt * 16 + lrow;
        float v = acc[mt][nt][r] + (bias ? bias[gcol] : 0.f);
        C[(size_t)grow * M + gcol] = f2bf(v);
      }
    }
  }
}

// ---------------- fused message GEMM v5 (unchanged from round 8: ~ceiling) ------
__global__ __launch_bounds__(512, 4) void msg_gemm(
    const int* __restrict__ offs, const unsigned short* __restrict__ sorted,
    const unsigned short* __restrict__ hb, const unsigned short* __restrict__ Wt_l,
    const float* __restrict__ bm_l, unsigned short* __restrict__ m) {
  constexpr int CH = 2568;                    // Ss chunk stride (shorts)
  __shared__ unsigned short Ss[8 * CH];       // 41.1 KB
  __shared__ unsigned short Bs[2][256 * 32];  // 32 KB ping-pong
  __shared__ unsigned short idxS[2048];       // 4 KB edge indices
  __shared__ int offsS[516];                  // 2 KB offs segment
  const int tid = threadIdx.x;
  const int lane = tid & 63;
  const int wv = tid >> 6;            // 0..7
  const int lrow = lane & 15;
  const int lquad = lane >> 4;
  const int wrow = wv & 3;            // dst 16-group
  const int wcol = wv >> 2;           // col half (128 cols)
  const int bm0 = blockIdx.x * 64;
  const int gg = wv * 4 + lquad;      // gather group 0..31
  const int brow = tid >> 2;          // 0..127 (Bs staging row)
  const int bcol = (tid & 3) * 8;

  // ---- stage offs + edge-index segments ----
  const int gseg0 = offs[bm0 * 8];
  const int gseg1 = offs[bm0 * 8 + 512];
  const int seg = gseg1 - gseg0;
  for (int i = tid; i < 513; i += 512) offsS[i] = offs[bm0 * 8 + i];
  const int segc = seg < 2048 ? seg : 2048;
  for (int i = tid; i < segc; i += 512) idxS[i] = sorted[gseg0 + i];
  const bool useLds = (seg <= 2048);
  const unsigned short* ip = useLds ? (const unsigned short*)idxS : (sorted + gseg0);
  __syncthreads();

  f32x4 acc[8] = {};
  int buf = 0;

  for (int t = 0; t < T_TYPES; ++t) {
    // ---- phase A: build S_t (64 x 256) in LDS ----
    #pragma unroll
    for (int step = 0; step < 2; ++step) {
      const int dloc = gg + step * 32;
      const int beg = offsS[dloc * 8 + t] - gseg0;
      const int end = offsS[dloc * 8 + t + 1] - gseg0;
      float a[16];
      #pragma unroll
      for (int j = 0; j < 16; ++j) a[j] = 0.f;
      int e = beg;
      if (e + 2 <= end) {
        int s0 = ip[e], s1 = ip[e + 1];
        const unsigned short* h0 = hb + (size_t)s0 * H_DIM + lrow * 16;
        const unsigned short* h1 = hb + (size_t)s1 * H_DIM + lrow * 16;
        uint4 pv0 = *(const uint4*)h0, pw0 = *(const uint4*)(h0 + 8);
        uint4 pv1 = *(const uint4*)h1, pw1 = *(const uint4*)(h1 + 8);
        e += 2;
        for (; e + 2 <= end; e += 2) {
          const int n0 = ip[e], n1 = ip[e + 1];
          const unsigned short* g0 = hb + (size_t)n0 * H_DIM + lrow * 16;
          const unsigned short* g1 = hb + (size_t)n1 * H_DIM + lrow * 16;
          const uint4 nv0 = *(const uint4*)g0, nw0 = *(const uint4*)(g0 + 8);
          const uint4 nv1 = *(const uint4*)g1, nw1 = *(const uint4*)(g1 + 8);
          acc16(a, pv0, pw0);
          acc16(a, pv1, pw1);
          pv0 = nv0; pw0 = nw0; pv1 = nv1; pw1 = nw1;
        }
        acc16(a, pv0, pw0);
        acc16(a, pv1, pw1);
      }
      if (e < end) {
        const int s0 = ip[e];
        const unsigned short* h0 = hb + (size_t)s0 * H_DIM + lrow * 16;
        acc16(a, *(const uint4*)h0, *(const uint4*)(h0 + 8));
      }
      union { unsigned short us[16]; uint4 q[2]; } ob;
      #pragma unroll
      for (int j = 0; j < 16; ++j) ob.us[j] = f2bf(a[j]);
      uint4* p = (uint4*)&Ss[(lrow >> 1) * CH + dloc * 40 + (lrow & 1) * 16];
      p[0] = ob.q[0];
      p[1] = ob.q[1];
    }
    // stage Bs for kc=0 of this type
    const unsigned short* Wt = Wt_l + (size_t)t * 65536;
    gload_lds16(Wt + (size_t)brow * 256 + bcol, &Bs[buf][brow * 32 + bcol]);
    gload_lds16(Wt + (size_t)(brow + 128) * 256 + bcol, &Bs[buf][(brow + 128) * 32 + bcol]);
    __syncthreads();
    // ---- phase B: acc += S_t @ Wm[t]^T, dbuf Bs, 1 barrier/kc ----
    for (int kc = 0; kc < 8; ++kc) {
      if (kc < 7) {  // prefetch kc+1 into other buffer (overlaps MFMA below)
        gload_lds16(Wt + (size_t)brow * 256 + (kc + 1) * 32 + bcol,
                    &Bs[buf ^ 1][brow * 32 + bcol]);
        gload_lds16(Wt + (size_t)(brow + 128) * 256 + (kc + 1) * 32 + bcol,
                    &Bs[buf ^ 1][(brow + 128) * 32 + bcol]);
      }
      const bf16x8 af = *(const bf16x8*)(&Ss[kc * CH + (wrow * 16 + lrow) * 40 + lquad * 8]);
      #pragma unroll
      for (int nt = 0; nt < 8; ++nt) {
        const bf16x8 b = *(const bf16x8*)(&Bs[buf][((wcol * 8 + nt) * 16 + lrow) * 32 + lquad * 8]);
        acc[nt] = __builtin_amdgcn_mfma_f32_16x16x32_bf16(af, b, acc[nt], 0, 0, 0);
      }
      buf ^= 1;
      __syncthreads();   // drains prefetch + protects Bs/Ss reuse
    }
  }

  // ---- epilogue: m = acc + sum_t cnt[dst,t]*bm[t,:]; cnt from offsS deltas ----
  float cnt[4][8];
  #pragma unroll
  for (int r = 0; r < 4; ++r) {
    const int dl = wrow * 16 + lquad * 4 + r;
    #pragma unroll
    for (int t = 0; t < 8; ++t)
      cnt[r][t] = (float)(offsS[dl * 8 + t + 1] - offsS[dl * 8 + t]);
  }
  #pragma unroll
  for (int nt = 0; nt < 8; ++nt) {
    const int gcol = wcol * 128 + nt * 16 + lrow;
    float bmv[8];
    #pragma unroll
    for (int t = 0; t < 8; ++t) bmv[t] = bm_l[t * H_DIM + gcol];
    #pragma unroll
    for (int r = 0; r < 4; ++r) {
      const int grow = bm0 + wrow * 16 + lquad * 4 + r;
      float v = acc[nt][r];
      #pragma unroll
      for (int t = 0; t < 8; ++t) v += cnt[r][t] * bmv[t];
      m[(size_t)grow * H_DIM + gcol] = f2bf(v);
    }
  }
}

// ---------------- fused GRU v3: single pass, combined r/z accumulators ----------
// Block = 32 nodes x ALL 256 cols (m,h staged ONCE -> kills the 4x re-staging
// of the y-split version: -100 MB/layer). 4 acc planes via GRU identities:
//   racc = m@Wih_r^T + h@Whh_r^T   zacc likewise   nacc = m@Wih_n^T
//   hnacc = h@Whh_n^T ; n = tanh(nacc+b_in + r*(hnacc+b_hn))
// 4 waves x 64 cols each; B-frags direct from XCD-L2 (weights 786 KB).
// acc = 4 planes x 2 mt x 4 nt x f32x4 = 128 VGPRs.
__global__ __launch_bounds__(256, 2) void gru_fused(
    const unsigned short* __restrict__ mB,
    const unsigned short* __restrict__ hin,
    const unsigned short* __restrict__ wih_l,
    const unsigned short* __restrict__ whh_l,
    const float* __restrict__ bih_l,
    const float* __restrict__ bhh_l,
    unsigned short* __restrict__ hout) {
  __shared__ unsigned short Am[32 * 32];   // 2 KB
  __shared__ unsigned short Ah[32 * 32];   // 2 KB
  const int tid = threadIdx.x;
  const int lane = tid & 63;
  const int wv = tid >> 6;              // 0..3 -> col group c0 = wv*64
  const int lrow = lane & 15;
  const int lquad = lane >> 4;
  const int n0 = blockIdx.x * 32;
  const int c0 = wv * 64;
  const int srow = (tid & 127) >> 2;    // 0..31
  const int scol = (tid & 3) * 8;

  f32x4 racc[2][4] = {}, zacc[2][4] = {}, nacc[2][4] = {}, hnacc[2][4] = {};

  for (int kt = 0; kt < 256; kt += 32) {
    __syncthreads();   // prev iter's Am/Ah reads complete
    if (tid < 128) gload_lds16(mB  + (size_t)(n0 + srow) * 256 + kt + scol, &Am[srow * 32 + scol]);
    else           gload_lds16(hin + (size_t)(n0 + srow) * 256 + kt + scol, &Ah[srow * 32 + scol]);
    __syncthreads();
    bf16x8 am[2], ah[2];
    #pragma unroll
    for (int mt = 0; mt < 2; ++mt) {
      am[mt] = *(const bf16x8*)(&Am[(mt * 16 + lrow) * 32 + lquad * 8]);
      ah[mt] = *(const bf16x8*)(&Ah[(mt * 16 + lrow) * 32 + lquad * 8]);
    }
    #pragma unroll
    for (int nt = 0; nt < 4; ++nt) {
      const int wr = c0 + nt * 16 + lrow;   // weight row = output col
      const size_t ko = kt + lquad * 8;
      const bf16x8 bir = *(const bf16x8*)(wih_l + (size_t)(0 * 256 + wr) * 256 + ko);
      const bf16x8 biz = *(const bf16x8*)(wih_l + (size_t)(1 * 256 + wr) * 256 + ko);
      const bf16x8 bin_ = *(const bf16x8*)(wih_l + (size_t)(2 * 256 + wr) * 256 + ko);
      const bf16x8 bhr = *(const bf16x8*)(whh_l + (size_t)(0 * 256 + wr) * 256 + ko);
      const bf16x8 bhz = *(const bf16x8*)(whh_l + (size_t)(1 * 256 + wr) * 256 + ko);
      const bf16x8 bhn = *(const bf16x8*)(whh_l + (size_t)(2 * 256 + wr) * 256 + ko);
      #pragma unroll
      for (int mt = 0; mt < 2; ++mt) {
        racc[mt][nt]  = __builtin_amdgcn_mfma_f32_16x16x32_bf16(am[mt], bir,  racc[mt][nt], 0, 0, 0);
        zacc[mt][nt]  = __builtin_amdgcn_mfma_f32_16x16x32_bf16(am[mt], biz,  zacc[mt][nt], 0, 0, 0);
        nacc[mt][nt]  = __builtin_amdgcn_mfma_f32_16x16x32_bf16(am[mt], bin_, nacc[mt][nt], 0, 0, 0);
        racc[mt][nt]  = __builtin_amdgcn_mfma_f32_16x16x32_bf16(ah[mt], bhr,  racc[mt][nt], 0, 0, 0);
        zacc[mt][nt]  = __builtin_amdgcn_mfma_f32_16x16x32_bf16(ah[mt], bhz,  zacc[mt][nt], 0, 0, 0);
        hnacc[mt][nt] = __builtin_amdgcn_mfma_f32_16x16x32_bf16(ah[mt], bhn,  hnacc[mt][nt], 0, 0, 0);
      }
    }
  }

  #pragma unroll
  for (int nt = 0; nt < 4; ++nt) {
    const int c = c0 + nt * 16 + lrow;
    const float b_ir = bih_l[c], b_iz = bih_l[256 + c], b_in = bih_l[512 + c];
    const float b_hr = bhh_l[c], b_hz = bhh_l[256 + c], b_hn = bhh_l[512 + c];
    #pragma unroll
    for (int mt = 0; mt < 2; ++mt) {
      #pragma unroll
      for (int r = 0; r < 4; ++r) {
        const int node = n0 + mt * 16 + lquad * 4 + r;
        const float rr = 1.f / (1.f + __expf(-(racc[mt][nt][r] + b_ir + b_hr)));
        const float zz = 1.f / (1.f + __expf(-(zacc[mt][nt][r] + b_iz + b_hz)));
        const float nn = tanhf(nacc[mt][nt][r] + b_in + rr * (hnacc[mt][nt][r] + b_hn));
        const float hp = bf2f(hin[(size_t)node * 256 + c]);
        hout[(size_t)node * 256 + c] = f2bf((1.f - zz) * nn + zz * hp);
      }
    }
  }
}

// ---------------- readout ----------------
__global__ __launch_bounds__(256) void readout_partial(const unsigned short* __restrict__ hb,
                                                       float* __restrict__ part) {
  const int b = blockIdx.x >> 3;
  const int ch = blockIdx.x & 7;
  const int c = threadIdx.x;
  const unsigned short* base = hb + ((size_t)b * MAXN_ + ch * 128) * H_DIM + c;
  float s = 0.f;
  #pragma unroll 4
  for (int i = 0; i < 128; ++i) s += bf2f(base[(size_t)i * H_DIM]);
  part[(size_t)blockIdx.x * H_DIM + c] = s;
}

__global__ __launch_bounds__(256) void readout_final(const float* __restrict__ part,
                                                     float* __restrict__ out) {
  const int b = blockIdx.x;
  const int c = threadIdx.x;
  float s = 0.f;
  #pragma unroll
  for (int i = 0; i < 8; ++i) s += part[((size_t)b * 8 + i) * H_DIM + c];
  out[b * H_DIM + c] = s;
}

// ---------------- launch ----------------
extern "C" void kernel_launch(void* const* d_in, const int* in_sizes, int n_in,
                              void* d_out, int out_size, void* d_ws, size_t ws_size,
                              hipStream_t stream) {
  if (ws_size < WS_REQUIRED) return;  // diagnostic no-op guard

  const float* X   = (const float*)d_in[0];
  const int*   ei  = (const int*)d_in[1];
  const int*   et  = (const int*)d_in[2];
  const float* Wp  = (const float*)d_in[3];
  const float* bp  = (const float*)d_in[4];
  const float* Wm  = (const float*)d_in[5];
  const float* bm  = (const float*)d_in[6];
  const float* Wih = (const float*)d_in[7];
  const float* Whh = (const float*)d_in[8];
  const float* bih = (const float*)d_in[9];
  const float* bhh = (const float*)d_in[10];
  float* out = (float*)d_out;
  char* ws = (char*)d_ws;

  // BIG aliases (stream-ordered liveness)
  int*            counts = (int*)(ws + OFF_BIG);
  int*            cursor = (int*)(ws + OFF_BIG + REL_CURSOR);
  int*            bsum   = (int*)(ws + OFF_BIG + REL_BSUM);
  unsigned short* xpad   = (unsigned short*)(ws + OFF_BIG);
  unsigned short* wppad  = (unsigned short*)(ws + OFF_BIG + REL_WPPAD);
  unsigned short* h_alt  = (unsigned short*)(ws + OFF_BIG + REL_HALT);
  float*          part   = (float*)(ws + OFF_BIG);
  int*            offs   = (int*)(ws + OFF_BIG + REL_OFFS);
  unsigned short* sorted = (unsigned short*)(ws + OFF_BIG + REL_SORTED);
  // persistent
  unsigned short* h_b    = (unsigned short*)(ws + OFF_H_B);
  unsigned short* m_b    = (unsigned short*)(ws + OFF_M_B);
  unsigned short* wmb    = (unsigned short*)(ws + OFF_WMB);
  unsigned short* wih_b  = (unsigned short*)(ws + OFF_WIH);
  unsigned short* whh_b  = (unsigned short*)(ws + OFF_WHH);

  const int* src = ei;
  const int* dst = ei + E_EDGES;

  // ---- counting sort of edges by (dst*8 + type), once ----
  hipMemsetAsync(counts, 0, NT_BINS * sizeof(int), stream);
  hist_kernel<<<E_EDGES / 256, 256, 0, stream>>>(dst, et, counts);
  scan1<<<NT_BINS / 1024, 1024, 0, stream>>>(counts, offs, bsum);
  scan2<<<1, 256, 0, stream>>>(bsum);
  scan3<<<NT_BINS / 1024, 1024, 0, stream>>>(offs, bsum, cursor);
  reorder_kernel<<<E_EDGES / 256, 256, 0, stream>>>(src, dst, et, cursor, sorted);

  // ---- weight/input conversion to bf16 (one fused launch for the 3 weight sets) ----
  pad_cvt<<<(N_NODES * 256) / 256, 256, 0, stream>>>(X, xpad, N_NODES, F_IN);
  pad_cvt<<<(256 * 256) / 256, 256, 0, stream>>>(Wp, wppad, 256, F_IN);
  {
    const int na = L_LAYERS * T_TYPES * H_DIM * H_DIM;   // 1572864
    const int nb = L_LAYERS * 3 * H_DIM * H_DIM;         // 589824
    const int nc = nb;
    cvt_weights<<<(na + nb + nc + 255) / 256, 256, 0, stream>>>(
        Wm, Wih, Whh, wmb, wih_b, whh_b, na, nb, nc);
  }

  // ---- input projection: h = X @ Wp^T + bp ----
  gemm_bt<<<dim3(N_NODES / 128, 2), 256, 0, stream>>>(xpad, wppad, bp, h_b, H_DIM, 256);

  for (int l = 0; l < L_LAYERS; ++l) {
    const unsigned short* wm_l  = wmb + (size_t)l * T_TYPES * H_DIM * H_DIM;
    const unsigned short* wih_l = wih_b + (size_t)l * 3 * H_DIM * H_DIM;
    const unsigned short* whh_l = whh_b + (size_t)l * 3 * H_DIM * H_DIM;
    const float* bm_l  = bm + (size_t)l * T_TYPES * H_DIM;
    const float* bih_l = bih + (size_t)l * 3 * H_DIM;
    const float* bhh_l = bhh + (size_t)l * 3 * H_DIM;

    unsigned short* h_cur = (l & 1) ? h_alt : h_b;
    unsigned short* h_nxt = (l & 1) ? h_b : h_alt;

    // fused: m = (scatter-sum_t h) @ Wm^T + cnt-weighted bm  (S stays in LDS)
    msg_gemm<<<N_NODES / 64, 512, 0, stream>>>(offs, sorted, h_cur, wm_l, bm_l, m_b);
    // fused: h_nxt = GRU(m, h_cur)  (m/h staged once per block; gi/gh in registers)
    gru_fused<<<N_NODES / 32, 256, 0, stream>>>(
        m_b, h_cur, wih_l, whh_l, bih_l, bhh_l, h_nxt);
  }

  // final h is in h_alt (l=2 writes h_alt); part at BIG+0 is disjoint
  readout_partial<<<B_GRAPHS * 8, 256, 0, stream>>>(h_alt, part);
  readout_final<<<B_GRAPHS, 256, 0, stream>>>(part, out);

  (void)in_sizes; (void)n_in; (void)out_size;
}

// Round 10
// 627.990 us; speedup vs baseline: 1.2490x; 1.2490x over previous
//
#include <hip/hip_runtime.h>

// ---------------- problem constants ----------------
#define N_NODES 32768
#define E_EDGES 524288
#define F_IN    215
#define H_DIM   256
#define T_TYPES 8
#define L_LAYERS 3
#define B_GRAPHS 32
#define MAXN_   1024
#define NT_BINS (N_NODES * T_TYPES)   // 262144

typedef float  f32x4  __attribute__((ext_vector_type(4)));
typedef __bf16 bf16x8 __attribute__((ext_vector_type(8)));

__device__ __forceinline__ unsigned short f2bf(float f) {
  union { float f; unsigned u; } v; v.f = f;
  unsigned r = v.u + 0x7fffu + ((v.u >> 16) & 1u);
  return (unsigned short)(r >> 16);
}
__device__ __forceinline__ float bf2f(unsigned short h) {
  union { unsigned u; float f; } v; v.u = ((unsigned)h) << 16;
  return v.f;
}
__device__ __forceinline__ float bflo(unsigned u) { union { unsigned x; float f; } v; v.x = u << 16; return v.f; }
__device__ __forceinline__ float bfhi(unsigned u) { union { unsigned x; float f; } v; v.x = u & 0xffff0000u; return v.f; }

typedef const __attribute__((address_space(1))) unsigned int* gas_ptr;
typedef __attribute__((address_space(3))) unsigned int* las_ptr;
__device__ __forceinline__ void gload_lds16(const unsigned short* g, unsigned short* l) {
  __builtin_amdgcn_global_load_lds((gas_ptr)g, (las_ptr)l, 16, 0, 0);
}

__device__ __forceinline__ void acc16(float* a, const uint4 v, const uint4 w) {
  a[0]  += bflo(v.x); a[1]  += bfhi(v.x);
  a[2]  += bflo(v.y); a[3]  += bfhi(v.y);
  a[4]  += bflo(v.z); a[5]  += bfhi(v.z);
  a[6]  += bflo(v.w); a[7]  += bfhi(v.w);
  a[8]  += bflo(w.x); a[9]  += bfhi(w.x);
  a[10] += bflo(w.y); a[11] += bfhi(w.y);
  a[12] += bflo(w.z); a[13] += bfhi(w.z);
  a[14] += bflo(w.w); a[15] += bfhi(w.w);
}

// ---------------- ws layout (bytes) ----------------
static constexpr size_t OFF_BIG     = 0;            // 134217728
static constexpr size_t REL_CURSOR  = 1048576;
static constexpr size_t REL_BSUM    = 2097152;
static constexpr size_t REL_WPPAD   = 33554432;
static constexpr size_t REL_HALT    = 50331648;
static constexpr size_t REL_OFFS    = 100663296;
static constexpr size_t REL_SORTED  = 104857600;
static constexpr size_t OFF_H_B     = 134217728;    // 16777216   h bf16 (N,H)
static constexpr size_t OFF_M_B     = 150994944;    // 16777216   m bf16 (N,H)
static constexpr size_t OFF_WMB     = 167772160;    // 3145728    Wm bf16 (L,T,H,H) natural
static constexpr size_t OFF_WIH     = 170917888;    // 1179648    Wih bf16
static constexpr size_t OFF_WHH     = 172097536;    // 1179648    Whh bf16
static constexpr size_t WS_REQUIRED = 173277184;    // < 175.9 MB proven safe

// ---------------- edge preprocessing: counting sort by key=(dst*8+type) ----------------
__global__ void hist_kernel(const int* __restrict__ dst, const int* __restrict__ et,
                            int* __restrict__ cnt) {
  int e = blockIdx.x * 256 + threadIdx.x;
  atomicAdd(&cnt[dst[e] * T_TYPES + et[e]], 1);
}

__global__ __launch_bounds__(1024) void scan1(const int* __restrict__ cnt,
                                              int* __restrict__ offs,
                                              int* __restrict__ bsum) {
  __shared__ int wsum[16];
  const int t = threadIdx.x, lane = t & 63, wid = t >> 6;
  const int idx = blockIdx.x * 1024 + t;
  const int v = cnt[idx];
  int x = v;
  #pragma unroll
  for (int off = 1; off < 64; off <<= 1) {
    int u = __shfl_up(x, off, 64);
    if (lane >= off) x += u;
  }
  if (lane == 63) wsum[wid] = x;
  __syncthreads();
  int wbase = 0;
  for (int i = 0; i < wid; ++i) wbase += wsum[i];
  offs[idx] = wbase + x - v;
  if (t == 1023) bsum[blockIdx.x] = wbase + x;
}

__global__ __launch_bounds__(256) void scan2(int* __restrict__ bsum) {
  __shared__ int wsum[4];
  const int t = threadIdx.x, lane = t & 63, wid = t >> 6;
  const int v = bsum[t];
  int x = v;
  #pragma unroll
  for (int off = 1; off < 64; off <<= 1) {
    int u = __shfl_up(x, off, 64);
    if (lane >= off) x += u;
  }
  if (lane == 63) wsum[wid] = x;
  __syncthreads();
  int wbase = 0;
  for (int i = 0; i < wid; ++i) wbase += wsum[i];
  __syncthreads();
  bsum[t] = wbase + x - v;
}

__global__ __launch_bounds__(1024) void scan3(int* __restrict__ offs,
                                              const int* __restrict__ bsum,
                                              int* __restrict__ cursor) {
  const int idx = blockIdx.x * 1024 + threadIdx.x;
  const int o = offs[idx] + bsum[blockIdx.x];
  offs[idx] = o;
  cursor[idx] = o;
  if (idx == 0) offs[NT_BINS] = E_EDGES;
}

__global__ void reorder_kernel(const int* __restrict__ src, const int* __restrict__ dst,
                               const int* __restrict__ et, int* __restrict__ cursor,
                               unsigned short* __restrict__ sorted) {
  int e = blockIdx.x * 256 + threadIdx.x;
  int key = dst[e] * T_TYPES + et[e];
  int p = atomicAdd(&cursor[key], 1);
  sorted[p] = (unsigned short)src[e];
}

// ---------------- conversions ----------------
__global__ void cvt_weights(const float* __restrict__ a, const float* __restrict__ b,
                            const float* __restrict__ c,
                            unsigned short* __restrict__ oa, unsigned short* __restrict__ ob,
                            unsigned short* __restrict__ oc,
                            int na, int nb, int nc) {
  int i = blockIdx.x * 256 + threadIdx.x;
  if (i < na) { oa[i] = f2bf(a[i]); return; }
  int j = i - na;
  if (j < nb) { ob[j] = f2bf(b[j]); return; }
  int k = j - nb;
  if (k < nc) oc[k] = f2bf(c[k]);
}

__global__ void pad_cvt(const float* __restrict__ in, unsigned short* __restrict__ out,
                        int rows, int cin) {
  int i = blockIdx.x * 256 + threadIdx.x;
  if (i >= rows * 256) return;
  int r = i >> 8, c = i & 255;
  out[i] = (c < cin) ? f2bf(in[(size_t)r * cin + c]) : (unsigned short)0;
}

// ---------------- GEMM: C(N x M) = A(N x K) @ W(M x K)^T + bias (input proj) ------
__global__ __launch_bounds__(256, 2) void gemm_bt(
    const unsigned short* __restrict__ A,
    const unsigned short* __restrict__ W,
    const float* __restrict__ bias,
    unsigned short* __restrict__ C,
    int M, int K) {
  __shared__ unsigned short As[128 * 32];
  __shared__ unsigned short Bs[128 * 32];
  const int tid = threadIdx.x;
  const int lane = tid & 63;
  const int wv = tid >> 6;
  const int lrow = lane & 15;
  const int lquad = lane >> 4;
  const int bm0 = blockIdx.x * 128;
  const int bn0 = blockIdx.y * 128;
  const int srow = wv * 16 + (lane >> 2);
  const int scol = (lane & 3) * 8;

  f32x4 acc[2][8] = {};

  for (int kt = 0; kt < K; kt += 32) {
    #pragma unroll
    for (int i = 0; i < 2; ++i) {
      const int row = srow + i * 64;
      gload_lds16(A + (size_t)(bm0 + row) * K + kt + scol, &As[row * 32 + scol]);
      gload_lds16(W + (size_t)(bn0 + row) * K + kt + scol, &Bs[row * 32 + scol]);
    }
    __syncthreads();
    bf16x8 af[2], bfr[8];
    #pragma unroll
    for (int mt = 0; mt < 2; ++mt)
      af[mt] = *(const bf16x8*)(&As[(wv * 32 + mt * 16 + lrow) * 32 + lquad * 8]);
    #pragma unroll
    for (int nt = 0; nt < 8; ++nt)
      bfr[nt] = *(const bf16x8*)(&Bs[(nt * 16 + lrow) * 32 + lquad * 8]);
    #pragma unroll
    for (int mt = 0; mt < 2; ++mt)
      #pragma unroll
      for (int nt = 0; nt < 8; ++nt)
        acc[mt][nt] = __builtin_amdgcn_mfma_f32_16x16x32_bf16(af[mt], bfr[nt], acc[mt][nt], 0, 0, 0);
    __syncthreads();
  }

  #pragma unroll
  for (int mt = 0; mt < 2; ++mt) {
    #pragma unroll
    for (int r = 0; r < 4; ++r) {
      const int grow = bm0 + wv * 32 + mt * 16 + lquad * 4 + r;
      #pragma unroll
      for (int nt = 0; nt < 8; ++nt) {
        const int gcol = bn0 + nt * 16 + lrow;
        float v = acc[mt][nt][r] + (bias ? bias[gcol] : 0.f);
        C[(size_t)grow * M + gcol] = f2bf(v);
      }
    }
  }
}

// ---------------- fused message GEMM v5 (round-8 version: ~pattern ceiling) ------
__global__ __launch_bounds__(512, 4) void msg_gemm(
    const int* __restrict__ offs, const unsigned short* __restrict__ sorted,
    const unsigned short* __restrict__ hb, const unsigned short* __restrict__ Wt_l,
    const float* __restrict__ bm_l, unsigned short* __restrict__ m) {
  constexpr int CH = 2568;                    // Ss chunk stride (shorts)
  __shared__ unsigned short Ss[8 * CH];       // 41.1 KB
  __shared__ unsigned short Bs[2][256 * 32];  // 32 KB ping-pong
  __shared__ unsigned short idxS[2048];       // 4 KB edge indices
  __shared__ int offsS[516];                  // 2 KB offs segment
  const int tid = threadIdx.x;
  const int lane = tid & 63;
  const int wv = tid >> 6;            // 0..7
  const int lrow = lane & 15;
  const int lquad = lane >> 4;
  const int wrow = wv & 3;            // dst 16-group
  const int wcol = wv >> 2;           // col half (128 cols)
  const int bm0 = blockIdx.x * 64;
  const int gg = wv * 4 + lquad;      // gather group 0..31
  const int brow = tid >> 2;          // 0..127 (Bs staging row)
  const int bcol = (tid & 3) * 8;

  // ---- stage offs + edge-index segments ----
  const int gseg0 = offs[bm0 * 8];
  const int gseg1 = offs[bm0 * 8 + 512];
  const int seg = gseg1 - gseg0;
  for (int i = tid; i < 513; i += 512) offsS[i] = offs[bm0 * 8 + i];
  const int segc = seg < 2048 ? seg : 2048;
  for (int i = tid; i < segc; i += 512) idxS[i] = sorted[gseg0 + i];
  const bool useLds = (seg <= 2048);
  const unsigned short* ip = useLds ? (const unsigned short*)idxS : (sorted + gseg0);
  __syncthreads();

  f32x4 acc[8] = {};
  int buf = 0;

  for (int t = 0; t < T_TYPES; ++t) {
    // ---- phase A: build S_t (64 x 256) in LDS ----
    #pragma unroll
    for (int step = 0; step < 2; ++step) {
      const int dloc = gg + step * 32;
      const int beg = offsS[dloc * 8 + t] - gseg0;
      const int end = offsS[dloc * 8 + t + 1] - gseg0;
      float a[16];
      #pragma unroll
      for (int j = 0; j < 16; ++j) a[j] = 0.f;
      int e = beg;
      if (e + 2 <= end) {
        int s0 = ip[e], s1 = ip[e + 1];
        const unsigned short* h0 = hb + (size_t)s0 * H_DIM + lrow * 16;
        const unsigned short* h1 = hb + (size_t)s1 * H_DIM + lrow * 16;
        uint4 pv0 = *(const uint4*)h0, pw0 = *(const uint4*)(h0 + 8);
        uint4 pv1 = *(const uint4*)h1, pw1 = *(const uint4*)(h1 + 8);
        e += 2;
        for (; e + 2 <= end; e += 2) {
          const int n0 = ip[e], n1 = ip[e + 1];
          const unsigned short* g0 = hb + (size_t)n0 * H_DIM + lrow * 16;
          const unsigned short* g1 = hb + (size_t)n1 * H_DIM + lrow * 16;
          const uint4 nv0 = *(const uint4*)g0, nw0 = *(const uint4*)(g0 + 8);
          const uint4 nv1 = *(const uint4*)g1, nw1 = *(const uint4*)(g1 + 8);
          acc16(a, pv0, pw0);
          acc16(a, pv1, pw1);
          pv0 = nv0; pw0 = nw0; pv1 = nv1; pw1 = nw1;
        }
        acc16(a, pv0, pw0);
        acc16(a, pv1, pw1);
      }
      if (e < end) {
        const int s0 = ip[e];
        const unsigned short* h0 = hb + (size_t)s0 * H_DIM + lrow * 16;
        acc16(a, *(const uint4*)h0, *(const uint4*)(h0 + 8));
      }
      union { unsigned short us[16]; uint4 q[2]; } ob;
      #pragma unroll
      for (int j = 0; j < 16; ++j) ob.us[j] = f2bf(a[j]);
      uint4* p = (uint4*)&Ss[(lrow >> 1) * CH + dloc * 40 + (lrow & 1) * 16];
      p[0] = ob.q[0];
      p[1] = ob.q[1];
    }
    // stage Bs for kc=0 of this type
    const unsigned short* Wt = Wt_l + (size_t)t * 65536;
    gload_lds16(Wt + (size_t)brow * 256 + bcol, &Bs[buf][brow * 32 + bcol]);
    gload_lds16(Wt + (size_t)(brow + 128) * 256 + bcol, &Bs[buf][(brow + 128) * 32 + bcol]);
    __syncthreads();
    // ---- phase B: acc += S_t @ Wm[t]^T, dbuf Bs, 1 barrier/kc ----
    for (int kc = 0; kc < 8; ++kc) {
      if (kc < 7) {  // prefetch kc+1 into other buffer (overlaps MFMA below)
        gload_lds16(Wt + (size_t)brow * 256 + (kc + 1) * 32 + bcol,
                    &Bs[buf ^ 1][brow * 32 + bcol]);
        gload_lds16(Wt + (size_t)(brow + 128) * 256 + (kc + 1) * 32 + bcol,
                    &Bs[buf ^ 1][(brow + 128) * 32 + bcol]);
      }
      const bf16x8 af = *(const bf16x8*)(&Ss[kc * CH + (wrow * 16 + lrow) * 40 + lquad * 8]);
      #pragma unroll
      for (int nt = 0; nt < 8; ++nt) {
        const bf16x8 b = *(const bf16x8*)(&Bs[buf][((wcol * 8 + nt) * 16 + lrow) * 32 + lquad * 8]);
        acc[nt] = __builtin_amdgcn_mfma_f32_16x16x32_bf16(af, b, acc[nt], 0, 0, 0);
      }
      buf ^= 1;
      __syncthreads();   // drains prefetch + protects Bs/Ss reuse
    }
  }

  // ---- epilogue: m = acc + sum_t cnt[dst,t]*bm[t,:]; cnt from offsS deltas ----
  float cnt[4][8];
  #pragma unroll
  for (int r = 0; r < 4; ++r) {
    const int dl = wrow * 16 + lquad * 4 + r;
    #pragma unroll
    for (int t = 0; t < 8; ++t)
      cnt[r][t] = (float)(offsS[dl * 8 + t + 1] - offsS[dl * 8 + t]);
  }
  #pragma unroll
  for (int nt = 0; nt < 8; ++nt) {
    const int gcol = wcol * 128 + nt * 16 + lrow;
    float bmv[8];
    #pragma unroll
    for (int t = 0; t < 8; ++t) bmv[t] = bm_l[t * H_DIM + gcol];
    #pragma unroll
    for (int r = 0; r < 4; ++r) {
      const int grow = bm0 + wrow * 16 + lquad * 4 + r;
      float v = acc[nt][r];
      #pragma unroll
      for (int t = 0; t < 8; ++t) v += cnt[r][t] * bmv[t];
      m[(size_t)grow * H_DIM + gcol] = f2bf(v);
    }
  }
}

// ---------------- fused GRU (round-8 version, reverted): col-split waves, direct-B --
// Block: 64 nodes x 64 cols; wave w owns cols [c0+w*16,+16) so B-frags are
// per-wave-disjoint -> direct global loads (0.25 loads/MFMA; L2-resident
// weights; all 4 y-blocks of an x map to the SAME XCD since 512%8==0, so
// m/h re-staging is L2-served). gi/gh never hit HBM.
__global__ __launch_bounds__(256, 3) void gru_fused(
    const unsigned short* __restrict__ mB,
    const unsigned short* __restrict__ hin,
    const unsigned short* __restrict__ wih_l,
    const unsigned short* __restrict__ whh_l,
    const float* __restrict__ bih_l,
    const float* __restrict__ bhh_l,
    unsigned short* __restrict__ hout) {
  __shared__ unsigned short Am[64 * 32];   // 4 KB
  __shared__ unsigned short Ah[64 * 32];   // 4 KB
  const int tid = threadIdx.x;
  const int lane = tid & 63;
  const int wv = tid >> 6;
  const int lrow = lane & 15;
  const int lquad = lane >> 4;
  const int n0 = blockIdx.x * 64;
  const int c0 = blockIdx.y * 64;
  const int arow = tid >> 2;
  const int scol = (tid & 3) * 8;

  f32x4 acc[6][4] = {};

  for (int kt = 0; kt < 256; kt += 32) {
    __syncthreads();
    gload_lds16(mB  + (size_t)(n0 + arow) * 256 + kt + scol, &Am[arow * 32 + scol]);
    gload_lds16(hin + (size_t)(n0 + arow) * 256 + kt + scol, &Ah[arow * 32 + scol]);
    __syncthreads();
    const int wr = c0 + wv * 16 + lrow;
    bf16x8 bfr[6];
    #pragma unroll
    for (int g = 0; g < 3; ++g) {
      bfr[g]     = *(const bf16x8*)(wih_l + (size_t)(g * 256 + wr) * 256 + kt + lquad * 8);
      bfr[g + 3] = *(const bf16x8*)(whh_l + (size_t)(g * 256 + wr) * 256 + kt + lquad * 8);
    }
    #pragma unroll
    for (int mt = 0; mt < 4; ++mt) {
      const bf16x8 am = *(const bf16x8*)(&Am[(mt * 16 + lrow) * 32 + lquad * 8]);
      const bf16x8 ah = *(const bf16x8*)(&Ah[(mt * 16 + lrow) * 32 + lquad * 8]);
      #pragma unroll
      for (int g = 0; g < 6; ++g)
        acc[g][mt] = __builtin_amdgcn_mfma_f32_16x16x32_bf16(g < 3 ? am : ah, bfr[g], acc[g][mt], 0, 0, 0);
    }
  }

  const int c = c0 + wv * 16 + lrow;
  const float b_ir = bih_l[c], b_iz = bih_l[256 + c], b_in = bih_l[512 + c];
  const float b_hr = bhh_l[c], b_hz = bhh_l[256 + c], b_hn = bhh_l[512 + c];
  #pragma unroll
  for (int mt = 0; mt < 4; ++mt) {
    #pragma unroll
    for (int r = 0; r < 4; ++r) {
      const int node = n0 + mt * 16 + lquad * 4 + r;
      const float i_r = acc[0][mt][r] + b_ir;
      const float i_z = acc[1][mt][r] + b_iz;
      const float i_n = acc[2][mt][r] + b_in;
      const float h_r = acc[3][mt][r] + b_hr;
      const float h_z = acc[4][mt][r] + b_hz;
      const float h_n = acc[5][mt][r] + b_hn;
      const float rr = 1.f / (1.f + __expf(-(i_r + h_r)));
      const float zz = 1.f / (1.f + __expf(-(i_z + h_z)));
      const float nn = tanhf(i_n + rr * h_n);
      const float hp = bf2f(hin[(size_t)node * 256 + c]);
      hout[(size_t)node * 256 + c] = f2bf((1.f - zz) * nn + zz * hp);
    }
  }
}

// ---------------- readout ----------------
__global__ __launch_bounds__(256) void readout_partial(const unsigned short* __restrict__ hb,
                                                       float* __restrict__ part) {
  const int b = blockIdx.x >> 3;
  const int ch = blockIdx.x & 7;
  const int c = threadIdx.x;
  const unsigned short* base = hb + ((size_t)b * MAXN_ + ch * 128) * H_DIM + c;
  float s = 0.f;
  #pragma unroll 4
  for (int i = 0; i < 128; ++i) s += bf2f(base[(size_t)i * H_DIM]);
  part[(size_t)blockIdx.x * H_DIM + c] = s;
}

__global__ __launch_bounds__(256) void readout_final(const float* __restrict__ part,
                                                     float* __restrict__ out) {
  const int b = blockIdx.x;
  const int c = threadIdx.x;
  float s = 0.f;
  #pragma unroll
  for (int i = 0; i < 8; ++i) s += part[((size_t)b * 8 + i) * H_DIM + c];
  out[b * H_DIM + c] = s;
}

// ---------------- launch ----------------
extern "C" void kernel_launch(void* const* d_in, const int* in_sizes, int n_in,
                              void* d_out, int out_size, void* d_ws, size_t ws_size,
                              hipStream_t stream) {
  if (ws_size < WS_REQUIRED) return;  // diagnostic no-op guard

  const float* X   = (const float*)d_in[0];
  const int*   ei  = (const int*)d_in[1];
  const int*   et  = (const int*)d_in[2];
  const float* Wp  = (const float*)d_in[3];
  const float* bp  = (const float*)d_in[4];
  const float* Wm  = (const float*)d_in[5];
  const float* bm  = (const float*)d_in[6];
  const float* Wih = (const float*)d_in[7];
  const float* Whh = (const float*)d_in[8];
  const float* bih = (const float*)d_in[9];
  const float* bhh = (const float*)d_in[10];
  float* out = (float*)d_out;
  char* ws = (char*)d_ws;

  // BIG aliases (stream-ordered liveness)
  int*            counts = (int*)(ws + OFF_BIG);
  int*            cursor = (int*)(ws + OFF_BIG + REL_CURSOR);
  int*            bsum   = (int*)(ws + OFF_BIG + REL_BSUM);
  unsigned short* xpad   = (unsigned short*)(ws + OFF_BIG);
  unsigned short* wppad  = (unsigned short*)(ws + OFF_BIG + REL_WPPAD);
  unsigned short* h_alt  = (unsigned short*)(ws + OFF_BIG + REL_HALT);
  float*          part   = (float*)(ws + OFF_BIG);
  int*            offs   = (int*)(ws + OFF_BIG + REL_OFFS);
  unsigned short* sorted = (unsigned short*)(ws + OFF_BIG + REL_SORTED);
  // persistent
  unsigned short* h_b    = (unsigned short*)(ws + OFF_H_B);
  unsigned short* m_b    = (unsigned short*)(ws + OFF_M_B);
  unsigned short* wmb    = (unsigned short*)(ws + OFF_WMB);
  unsigned short* wih_b  = (unsigned short*)(ws + OFF_WIH);
  unsigned short* whh_b  = (unsigned short*)(ws + OFF_WHH);

  const int* src = ei;
  const int* dst = ei + E_EDGES;

  // ---- counting sort of edges by (dst*8 + type), once ----
  hipMemsetAsync(counts, 0, NT_BINS * sizeof(int), stream);
  hist_kernel<<<E_EDGES / 256, 256, 0, stream>>>(dst, et, counts);
  scan1<<<NT_BINS / 1024, 1024, 0, stream>>>(counts, offs, bsum);
  scan2<<<1, 256, 0, stream>>>(bsum);
  scan3<<<NT_BINS / 1024, 1024, 0, stream>>>(offs, bsum, cursor);
  reorder_kernel<<<E_EDGES / 256, 256, 0, stream>>>(src, dst, et, cursor, sorted);

  // ---- weight/input conversion to bf16 (one fused launch for the 3 weight sets) ----
  pad_cvt<<<(N_NODES * 256) / 256, 256, 0, stream>>>(X, xpad, N_NODES, F_IN);
  pad_cvt<<<(256 * 256) / 256, 256, 0, stream>>>(Wp, wppad, 256, F_IN);
  {
    const int na = L_LAYERS * T_TYPES * H_DIM * H_DIM;   // 1572864
    const int nb = L_LAYERS * 3 * H_DIM * H_DIM;         // 589824
    const int nc = nb;
    cvt_weights<<<(na + nb + nc + 255) / 256, 256, 0, stream>>>(
        Wm, Wih, Whh, wmb, wih_b, whh_b, na, nb, nc);
  }

  // ---- input projection: h = X @ Wp^T + bp ----
  gemm_bt<<<dim3(N_NODES / 128, 2), 256, 0, stream>>>(xpad, wppad, bp, h_b, H_DIM, 256);

  for (int l = 0; l < L_LAYERS; ++l) {
    const unsigned short* wm_l  = wmb + (size_t)l * T_TYPES * H_DIM * H_DIM;
    const unsigned short* wih_l = wih_b + (size_t)l * 3 * H_DIM * H_DIM;
    const unsigned short* whh_l = whh_b + (size_t)l * 3 * H_DIM * H_DIM;
    const float* bm_l  = bm + (size_t)l * T_TYPES * H_DIM;
    const float* bih_l = bih + (size_t)l * 3 * H_DIM;
    const float* bhh_l = bhh + (size_t)l * 3 * H_DIM;

    unsigned short* h_cur = (l & 1) ? h_alt : h_b;
    unsigned short* h_nxt = (l & 1) ? h_b : h_alt;

    // fused: m = (scatter-sum_t h) @ Wm^T + cnt-weighted bm  (S stays in LDS)
    msg_gemm<<<N_NODES / 64, 512, 0, stream>>>(offs, sorted, h_cur, wm_l, bm_l, m_b);
    // fused: h_nxt = GRU(m, h_cur)  (gi/gh stay in registers)
    gru_fused<<<dim3(N_NODES / 64, 4), 256, 0, stream>>>(
        m_b, h_cur, wih_l, whh_l, bih_l, bhh_l, h_nxt);
  }

  // final h is in h_alt (l=2 writes h_alt); part at BIG+0 is disjoint
  readout_partial<<<B_GRAPHS * 8, 256, 0, stream>>>(h_alt, part);
  readout_final<<<B_GRAPHS, 256, 0, stream>>>(part, out);

  (void)in_sizes; (void)n_in; (void)out_size;
}